// Round 1
// baseline (124.184 us; speedup 1.0000x reference)
//
#include <hip/hip_runtime.h>
#include <math.h>

// SemiConv2d: out[n,oc,h,w] = max_{ic,kh,kw} min(x_pad[n,ic,h+kh-1,w+kw-1], K[oc,ic,kh,kw])
// x: (8,32,96,96) f32, K: (32,32,3,3) f32, out: (8,32,96,96) f32, pad=-inf.
//
// VALU-bound: 288 min + ~144 max3 per output -> ~13us floor at 78.6e12 lane-ops/s.
// Block = 192 thr (3 waves): 48 w-cols (2 outputs each) x 4 thread-rows (2 h each),
// covering 96w x 8h x 4oc. Grid = 8n x 12ht x 8ocb = 768 blocks (3/CU).
// x staged in LDS per 4-ic chunk with -inf halo; K read with uniform indices
// (expect s_load -> SGPR operands for v_min_f32).

#define CIN 32
#define OCN 32
#define HH 96
#define WW 96
#define OT 4          // ocs per block
#define HT 8          // h rows per block
#define ICC 4         // ic chunk staged in LDS
#define LDS_STRIDE 100
#define LDS_IC (10 * LDS_STRIDE)

__global__ __launch_bounds__(192) void semiconv2d_kernel(
    const float* __restrict__ x, const float* __restrict__ kk,
    float* __restrict__ out)
{
    __shared__ float xs[ICC * LDS_IC];  // 4 * 1000 floats = 16 KB

    const int tid = threadIdx.x;
    const int b   = blockIdx.x;
    const int ocb = b & 7;              // fastest: oc-chunks share x in L2
    const int ht  = (b >> 3) % 12;
    const int n   = b / 96;
    const int h0  = ht * HT;
    const int oc0 = ocb * OT;

    const int c  = tid % 48;            // w-pair column
    const int tr = tid / 48;            // thread row (0..3), also staging ic
    const int w0 = 2 * c;

    float acc[OT][4];
#pragma unroll
    for (int i = 0; i < OT; ++i)
#pragma unroll
        for (int j = 0; j < 4; ++j) acc[i][j] = -INFINITY;

    for (int icb = 0; icb < CIN; icb += ICC) {
        __syncthreads();
        // side halo columns (col 1 = w=-1, col 98 = w=96)
        if (tid < ICC * 10) {
            int ic = tid / 10, rr = tid % 10;
            xs[ic * LDS_IC + rr * LDS_STRIDE + 1]  = -INFINITY;
            xs[ic * LDS_IC + rr * LDS_STRIDE + 98] = -INFINITY;
        }
        // row copy: thread (sic=tr, sc2=c) copies float2 per row; OOB rows -> -inf
        const float* xbase = x + (size_t)((n * CIN + icb + tr) * HH) * WW;
#pragma unroll
        for (int rr = 0; rr < 10; ++rr) {
            int hh = h0 - 1 + rr;
            float2 v;
            if (hh >= 0 && hh < HH) {
                v = *(const float2*)(xbase + hh * WW + 2 * c);
            } else {
                v = make_float2(-INFINITY, -INFINITY);
            }
            *(float2*)(&xs[tr * LDS_IC + rr * LDS_STRIDE + 2 + 2 * c]) = v;
        }
        __syncthreads();

#pragma unroll
        for (int ic = 0; ic < ICC; ++ic) {
            // register window: rows h-1..h+2, cols w-1..w+2 (LDS col = w+2)
            float xr[4][4];
            const int base = ic * LDS_IC + (2 * tr) * LDS_STRIDE + (2 * c + 1);
#pragma unroll
            for (int i = 0; i < 4; ++i)
#pragma unroll
                for (int j = 0; j < 4; ++j)
                    xr[i][j] = xs[base + i * LDS_STRIDE + j];

#pragma unroll
            for (int oc = 0; oc < OT; ++oc) {
                const float* kp = kk + (size_t)(((oc0 + oc) * CIN + icb + ic)) * 9;
                float kv[9];
#pragma unroll
                for (int t = 0; t < 9; ++t) kv[t] = kp[t];  // uniform -> s_load
#pragma unroll
                for (int kh = 0; kh < 3; ++kh)
#pragma unroll
                    for (int kw = 0; kw < 3; ++kw) {
                        float kvv = kv[kh * 3 + kw];
#pragma unroll
                        for (int a = 0; a < 2; ++a)
#pragma unroll
                            for (int bb = 0; bb < 2; ++bb)
                                acc[oc][a * 2 + bb] = fmaxf(acc[oc][a * 2 + bb],
                                                            fminf(xr[a + kh][bb + kw], kvv));
                    }
            }
        }
    }

    // epilogue: 8 x float2 stores
#pragma unroll
    for (int oc = 0; oc < OT; ++oc)
#pragma unroll
        for (int a = 0; a < 2; ++a) {
            int hh = h0 + 2 * tr + a;
            float2 v = make_float2(acc[oc][a * 2 + 0], acc[oc][a * 2 + 1]);
            *(float2*)(out + (size_t)(((n * OCN + oc0 + oc)) * HH + hh) * WW + w0) = v;
        }
}

extern "C" void kernel_launch(void* const* d_in, const int* in_sizes, int n_in,
                              void* d_out, int out_size, void* d_ws, size_t ws_size,
                              hipStream_t stream) {
    const float* x  = (const float*)d_in[0];
    const float* kk = (const float*)d_in[1];
    float* out      = (float*)d_out;
    semiconv2d_kernel<<<dim3(8 * 12 * 8), dim3(192), 0, stream>>>(x, kk, out);
}